// Round 9
// baseline (11720.441 us; speedup 1.0000x reference)
//
#include <hip/hip_runtime.h>

typedef unsigned short ushort_t;
typedef unsigned int uint_t;

using f16x8 = __attribute__((ext_vector_type(8))) _Float16;
using f16x2 = __attribute__((ext_vector_type(2))) _Float16;
using f32x4 = __attribute__((ext_vector_type(4))) float;
using u32x4 = __attribute__((ext_vector_type(4))) unsigned int;

#define BATCH 64
#define SEQT 512
#define DIN 256
#define HID 256
#define G4 1024   // 4*HID

static __device__ __forceinline__ ushort_t f16b(float x) {
    return __builtin_bit_cast(ushort_t, (_Float16)x);
}
static __device__ __forceinline__ uint_t pk2(float a, float b) {
    return (uint_t)f16b(a) | ((uint_t)f16b(b) << 16);
}
static __device__ __forceinline__ float sig_(float x) {
    return 1.f / (1.f + __expf(-x));
}
static __device__ __forceinline__ float tanh_(float x) {
    float e = __expf(2.f * x);
    return (e - 1.f) / (e + 1.f);
}

#define PINA(x) asm volatile("" : "+a"(x))
#define PINV(x) asm volatile("" : "+v"(x))

static __device__ __forceinline__ f16x8 asf16(u32x4 v) {
    return __builtin_bit_cast(f16x8, v);
}

// ---------------- prep kernels ----------------

__global__ void cvt_x_kernel(const float* __restrict__ in, ushort_t* __restrict__ out, int n4) {
    int i = blockIdx.x * blockDim.x + threadIdx.x;
    if (i < n4) {
        float4 v = ((const float4*)in)[i];
        ushort4 o;
        o.x = f16b(v.x); o.y = f16b(v.y); o.z = f16b(v.z); o.w = f16b(v.w);
        ((ushort4*)out)[i] = o;
    }
}

// W [256][1024] f32 -> Wt [1024][256] f16 bits (transpose)
__global__ void prep_wt_kernel(const float* __restrict__ W, ushort_t* __restrict__ Wt) {
    int tid = blockIdx.x * blockDim.x + threadIdx.x;
    int k = tid >> 10;
    int n = tid & 1023;
    Wt[n * DIN + k] = f16b(W[tid]);
}

// U0 [256][1024] f32 -> Upk [32][1024] uint4 (f16 pairs, k=8j..8j+7 per j)
__global__ void prep_upk_kernel(const float* __restrict__ U, uint4* __restrict__ Upk) {
    int tid = blockIdx.x * blockDim.x + threadIdx.x;
    int j = tid >> 10;
    int g = tid & 1023;
    uint4 o;
    uint_t* op = &o.x;
#pragma unroll
    for (int q = 0; q < 4; ++q) {
        float a = U[(8 * j + 2 * q) * G4 + g];
        float b = U[(8 * j + 2 * q + 1) * G4 + g];
        op[q] = pk2(a, b);
    }
    Upk[tid] = o;
}

// [W1;U1] combined -> Ucmb [64][1024] uint4 (K=512; j<32 from W1, j>=32 from U1)
__global__ void prep_ucmb_kernel(const float* __restrict__ W1, const float* __restrict__ U1,
                                 uint4* __restrict__ Ucmb) {
    int tid = blockIdx.x * blockDim.x + threadIdx.x;   // 65536
    int j = tid >> 10;
    int g = tid & 1023;
    const float* src = (j < 32) ? W1 : U1;
    int k0 = (j & 31) * 8;
    uint4 o;
    uint_t* op = &o.x;
#pragma unroll
    for (int q = 0; q < 4; ++q) {
        float a = src[(k0 + 2 * q) * G4 + g];
        float b = src[(k0 + 2 * q + 1) * G4 + g];
        op[q] = pk2(a, b);
    }
    Ucmb[tid] = o;
}

// ---------------- GEMM (unchanged, passing) ----------------

#define GSTRIDE 40

__global__ __launch_bounds__(256) void gemm_f16_kernel(
    const ushort_t* __restrict__ A,
    const ushort_t* __restrict__ Bt,
    const float* __restrict__ bias,
    float* __restrict__ C,
    int M)
{
    const int K = DIN, N = G4;
    __shared__ ushort_t As[128 * GSTRIDE];
    __shared__ ushort_t Bs[128 * GSTRIDE];
    int tid = threadIdx.x;
    int bx = blockIdx.x & 7;
    int by = blockIdx.x >> 3;
    int m0 = by * 128, n0 = bx * 128;
    int w = tid >> 6, lane = tid & 63;
    int wr = (w >> 1) * 64, wc = (w & 1) * 64;
    int r = lane & 15, kg = lane >> 4;

    f32x4 acc[4][4];
#pragma unroll
    for (int i = 0; i < 4; ++i)
#pragma unroll
        for (int j = 0; j < 4; ++j)
            acc[i][j] = f32x4{0.f, 0.f, 0.f, 0.f};

    for (int kt = 0; kt < K; kt += 32) {
        __syncthreads();
#pragma unroll
        for (int s = 0; s < 2; ++s) {
            int chunk = tid + s * 256;
            int row = chunk >> 2;
            int ko = (chunk & 3) * 8;
            uint4 va = *(const uint4*)(A + (size_t)(m0 + row) * K + kt + ko);
            *(uint4*)(&As[row * GSTRIDE + ko]) = va;
            uint4 vb = *(const uint4*)(Bt + (size_t)(n0 + row) * K + kt + ko);
            *(uint4*)(&Bs[row * GSTRIDE + ko]) = vb;
        }
        __syncthreads();
        f16x8 af[4], bf[4];
#pragma unroll
        for (int i = 0; i < 4; ++i) {
            af[i] = *(const f16x8*)(&As[(wr + i * 16 + r) * GSTRIDE + kg * 8]);
            bf[i] = *(const f16x8*)(&Bs[(wc + i * 16 + r) * GSTRIDE + kg * 8]);
        }
#pragma unroll
        for (int i = 0; i < 4; ++i)
#pragma unroll
            for (int j = 0; j < 4; ++j)
                acc[i][j] = __builtin_amdgcn_mfma_f32_16x16x32_f16(af[i], bf[j], acc[i][j], 0, 0, 0);
    }

#pragma unroll
    for (int i = 0; i < 4; ++i)
#pragma unroll
        for (int j = 0; j < 4; ++j) {
            int col = n0 + wc + j * 16 + r;
            float bv = bias[col];
#pragma unroll
            for (int v = 0; v < 4; ++v) {
                int rowg = m0 + wr + i * 16 + kg * 4 + v;
                C[(size_t)rowg * N + col] = acc[i][j][v] + bv;
            }
        }
}

// ---------------- fused 2-layer pipelined LSTM recurrence ----------------
// 128 WGs x 512 thr. Blocks 0-63: producer (layer 1, K=256, r8 structure).
// Blocks 64-127: consumer (layer 2, K=512 = [h1;h2]@[W1;U1]+b1).
// Handoff: producer stores h1[t] as 128 packed-u32 agent atomics + release
// flag (=t+1); consumer polls flag >= t+2 and prefetches h1[t+1] a full
// step ahead. Producer pace > consumer compute => consumer never stalls
// mid-step in steady state.

__global__ __launch_bounds__(512)
__attribute__((amdgpu_waves_per_eu(2, 2)))
void lstm_pipe_kernel(
    const float* __restrict__ xz1,    // [B*T][1024] layer-1 xz (bias incl)
    const u32x4* __restrict__ Upk0,   // [32][1024]
    const u32x4* __restrict__ Ucmb,   // [64][1024] (K=512 combined [W1;U1])
    const float* __restrict__ b1,     // [1024]
    uint_t* y1pk,                     // [B*T][128] packed h1 (u32 = 2 f16)
    int* flags,                       // [B][32] ints (128-B stride per row)
    float* __restrict__ out,          // [B*T][256]
    int T)
{
    __shared__ __align__(16) u32x4 Uld[8][2][8][64];    // 128 KB
    __shared__ __align__(16) ushort_t hbuf[2][512];     // 2 KB

    const int tid = threadIdx.x;      // 0..511
    const int w = tid >> 6;           // wave 0..7
    const int l = tid & 63;
    const int lg = l >> 4;            // k-subgroup 0..3
    const int lr = l & 15;
    const int role = (int)(blockIdx.x >> 6);   // 0 producer, 1 consumer
    const int b = (int)(blockIdx.x & 63);

    const int ti_sel = lg & 1;
    const int hcol = w * 32 + ti_sel * 16 + lr;
    const bool primary = (l < 32);
    const int w32 = w * 32;

    if (role == 0) {
        // ================= PRODUCER (layer 1) =================
        u32x4 ua[32];   // kt0-3 -> AGPR
        u32x4 uv[16];   // kt4-5 -> VGPR
#pragma unroll
        for (int gb = 0; gb < 4; ++gb)
#pragma unroll
            for (int ti = 0; ti < 2; ++ti) {
                int col = gb * 256 + w32 + ti * 16 + lr;
                int fi = gb * 2 + ti;
#pragma unroll
                for (int kt = 0; kt < 4; ++kt)
                    ua[kt * 8 + fi] = Upk0[(kt * 4 + lg) * 1024 + col];
#pragma unroll
                for (int k2 = 0; k2 < 2; ++k2)
                    uv[k2 * 8 + fi] = Upk0[((4 + k2) * 4 + lg) * 1024 + col];
            }
#pragma unroll
        for (int i = 0; i < 32; ++i) PINA(ua[i]);
#pragma unroll
        for (int i = 0; i < 16; ++i) PINV(uv[i]);

#pragma unroll
        for (int gb = 0; gb < 4; ++gb)
#pragma unroll
            for (int ti = 0; ti < 2; ++ti) {
                int col = gb * 256 + w32 + ti * 16 + lr;
#pragma unroll
                for (int k2 = 0; k2 < 2; ++k2)
                    Uld[w][k2][gb * 2 + ti][l] = Upk0[((6 + k2) * 4 + lg) * 1024 + col];
            }

        if (tid < 256) hbuf[0][tid] = 0;

        const float* xz_b = xz1 + (size_t)b * T * G4;
        float xzc[4];
#pragma unroll
        for (int gb = 0; gb < 4; ++gb) xzc[gb] = xz_b[gb * 256 + hcol];

        float c = 0.f;
        int* flagp = flags + b * 32;
        __syncthreads();

        for (int t = 0; t < T; ++t) {
            const int cur = t & 1, nxt = cur ^ 1;

            float xzn[4];
            {
                const float* xztn = xz_b + (size_t)((t + 1 < T) ? (t + 1) : t) * G4;
#pragma unroll
                for (int gb = 0; gb < 4; ++gb) xzn[gb] = xztn[gb * 256 + hcol];
            }

            f32x4 acc[4][2];
#pragma unroll
            for (int gb = 0; gb < 4; ++gb)
#pragma unroll
                for (int ti = 0; ti < 2; ++ti)
                    acc[gb][ti] = f32x4{0.f, 0.f, 0.f, 0.f};

            __builtin_amdgcn_s_setprio(1);
#pragma unroll
            for (int kt = 0; kt < 4; ++kt) {
                f16x8 af = *(const f16x8*)((const char*)&hbuf[cur][0] + kt * 64 + lg * 16);
#pragma unroll
                for (int gb = 0; gb < 4; ++gb)
#pragma unroll
                    for (int ti = 0; ti < 2; ++ti)
                        acc[gb][ti] = __builtin_amdgcn_mfma_f32_16x16x32_f16(
                            af, asf16(ua[kt * 8 + gb * 2 + ti]), acc[gb][ti], 0, 0, 0);
            }
#pragma unroll
            for (int k2 = 0; k2 < 2; ++k2) {
                f16x8 af = *(const f16x8*)((const char*)&hbuf[cur][0] + (4 + k2) * 64 + lg * 16);
#pragma unroll
                for (int gb = 0; gb < 4; ++gb)
#pragma unroll
                    for (int ti = 0; ti < 2; ++ti)
                        acc[gb][ti] = __builtin_amdgcn_mfma_f32_16x16x32_f16(
                            af, asf16(uv[k2 * 8 + gb * 2 + ti]), acc[gb][ti], 0, 0, 0);
            }
#pragma unroll
            for (int k2 = 0; k2 < 2; ++k2) {
                f16x8 af = *(const f16x8*)((const char*)&hbuf[cur][0] + (6 + k2) * 64 + lg * 16);
#pragma unroll
                for (int gb = 0; gb < 4; ++gb)
#pragma unroll
                    for (int ti = 0; ti < 2; ++ti) {
                        u32x4 ub = Uld[w][k2][gb * 2 + ti][l];
                        acc[gb][ti] = __builtin_amdgcn_mfma_f32_16x16x32_f16(
                            af, asf16(ub), acc[gb][ti], 0, 0, 0);
                    }
            }
            __builtin_amdgcn_s_setprio(0);

            float zg[4];
#pragma unroll
            for (int gb = 0; gb < 4; ++gb)
                zg[gb] = (ti_sel ? acc[gb][1][0] : acc[gb][0][0]) + xzc[gb];

            c = sig_(zg[1]) * c + sig_(zg[0]) * tanh_(zg[2]);
            float h = sig_(zg[3]) * tanh_(c);

            uint_t hb = (uint_t)f16b(h);
            uint_t pb = (uint_t)(unsigned)__shfl_xor((int)hb, 1);
            if (primary) {
                hbuf[nxt][hcol] = (ushort_t)hb;
                if (!(l & 1)) {
                    uint_t pk = hb | (pb << 16);
                    __hip_atomic_store(&y1pk[(size_t)(b * T + t) * 128 + (hcol >> 1)], pk,
                                       __ATOMIC_RELAXED, __HIP_MEMORY_SCOPE_AGENT);
                }
            }

#pragma unroll
            for (int gb = 0; gb < 4; ++gb) xzc[gb] = xzn[gb];

            __syncthreads();   // drains vmcnt: all data stores at coherence point
            if (tid == 0)
                __hip_atomic_store(flagp, t + 1, __ATOMIC_RELEASE, __HIP_MEMORY_SCOPE_AGENT);
        }
    } else {
        // ================= CONSUMER (layer 2, K=512) =================
        u32x4 ua[32];   // kt0-3 -> AGPR
#pragma unroll
        for (int gb = 0; gb < 4; ++gb)
#pragma unroll
            for (int ti = 0; ti < 2; ++ti) {
                int col = gb * 256 + w32 + ti * 16 + lr;
                int fi = gb * 2 + ti;
#pragma unroll
                for (int kt = 0; kt < 4; ++kt)
                    ua[kt * 8 + fi] = Ucmb[(kt * 4 + lg) * 1024 + col];
            }
#pragma unroll
        for (int i = 0; i < 32; ++i) PINA(ua[i]);

        // kt4-5 -> LDS
#pragma unroll
        for (int gb = 0; gb < 4; ++gb)
#pragma unroll
            for (int ti = 0; ti < 2; ++ti) {
                int col = gb * 256 + w32 + ti * 16 + lr;
#pragma unroll
                for (int k2 = 0; k2 < 2; ++k2)
                    Uld[w][k2][gb * 2 + ti][l] = Ucmb[((4 + k2) * 4 + lg) * 1024 + col];
            }

        const u32x4* sb = Ucmb + lg * 1024 + lr;   // + kt*4096 + gb*256 + w32 + ti*16

        float b1c[4];
#pragma unroll
        for (int gb = 0; gb < 4; ++gb) b1c[gb] = b1[gb * 256 + hcol];

        if (tid < 256) hbuf[0][256 + tid] = 0;     // h2(0) = 0

        int* flagp = flags + b * 32;
        // initial h1[0]
        while (__hip_atomic_load(flagp, __ATOMIC_ACQUIRE, __HIP_MEMORY_SCOPE_AGENT) < 1)
            __builtin_amdgcn_s_sleep(8);
        if (tid < 128) {
            uint_t h1r0 = __hip_atomic_load(&y1pk[(size_t)(b * T) * 128 + tid],
                                            __ATOMIC_RELAXED, __HIP_MEMORY_SCOPE_AGENT);
            ((uint_t*)&hbuf[0][0])[tid] = h1r0;
        }

        float c = 0.f;
        size_t obase = (size_t)b * T * HID + hcol;
        __syncthreads();

        for (int t = 0; t < T; ++t) {
            const int cur = t & 1, nxt = cur ^ 1;

            // prefetch h1[t+1] (a full step ahead; producer is pacer)
            uint_t h1r = 0;
            if (t + 1 < T) {
                while (__hip_atomic_load(flagp, __ATOMIC_ACQUIRE, __HIP_MEMORY_SCOPE_AGENT) < t + 2)
                    __builtin_amdgcn_s_sleep(8);
                if (tid < 128)
                    h1r = __hip_atomic_load(&y1pk[(size_t)(b * T + t + 1) * 128 + tid],
                                            __ATOMIC_RELAXED, __HIP_MEMORY_SCOPE_AGENT);
            }

            f32x4 acc[4][2];
#pragma unroll
            for (int gb = 0; gb < 4; ++gb)
#pragma unroll
                for (int ti = 0; ti < 2; ++ti)
                    acc[gb][ti] = f32x4{0.f, 0.f, 0.f, 0.f};

            // issue stream batches for kt6, kt7
            u32x4 us0[8], us1[8];
#pragma unroll
            for (int gb = 0; gb < 4; ++gb)
#pragma unroll
                for (int ti = 0; ti < 2; ++ti) {
                    us0[gb * 2 + ti] = sb[6 * 4096 + gb * 256 + w32 + ti * 16];
                    us1[gb * 2 + ti] = sb[7 * 4096 + gb * 256 + w32 + ti * 16];
                }

            __builtin_amdgcn_s_setprio(1);
#pragma unroll
            for (int kt = 0; kt < 4; ++kt) {
                f16x8 af = *(const f16x8*)((const char*)&hbuf[cur][0] + kt * 64 + lg * 16);
#pragma unroll
                for (int gb = 0; gb < 4; ++gb)
#pragma unroll
                    for (int ti = 0; ti < 2; ++ti)
                        acc[gb][ti] = __builtin_amdgcn_mfma_f32_16x16x32_f16(
                            af, asf16(ua[kt * 8 + gb * 2 + ti]), acc[gb][ti], 0, 0, 0);
            }
#pragma unroll
            for (int k2 = 0; k2 < 2; ++k2) {
                f16x8 af = *(const f16x8*)((const char*)&hbuf[cur][0] + (4 + k2) * 64 + lg * 16);
#pragma unroll
                for (int gb = 0; gb < 4; ++gb)
#pragma unroll
                    for (int ti = 0; ti < 2; ++ti) {
                        u32x4 ub = Uld[w][k2][gb * 2 + ti][l];
                        acc[gb][ti] = __builtin_amdgcn_mfma_f32_16x16x32_f16(
                            af, asf16(ub), acc[gb][ti], 0, 0, 0);
                    }
            }
            // streamed kt6..15 with 2 batches in flight
#pragma unroll
            for (int kt = 6; kt < 16; ++kt) {
                f16x8 af = *(const f16x8*)((const char*)&hbuf[cur][0] + kt * 64 + lg * 16);
                if (kt & 1) {
#pragma unroll
                    for (int gb = 0; gb < 4; ++gb)
#pragma unroll
                        for (int ti = 0; ti < 2; ++ti)
                            acc[gb][ti] = __builtin_amdgcn_mfma_f32_16x16x32_f16(
                                af, asf16(us1[gb * 2 + ti]), acc[gb][ti], 0, 0, 0);
                    if (kt + 2 < 16) {
#pragma unroll
                        for (int gb = 0; gb < 4; ++gb)
#pragma unroll
                            for (int ti = 0; ti < 2; ++ti)
                                us1[gb * 2 + ti] = sb[(kt + 2) * 4096 + gb * 256 + w32 + ti * 16];
                    }
                } else {
#pragma unroll
                    for (int gb = 0; gb < 4; ++gb)
#pragma unroll
                        for (int ti = 0; ti < 2; ++ti)
                            acc[gb][ti] = __builtin_amdgcn_mfma_f32_16x16x32_f16(
                                af, asf16(us0[gb * 2 + ti]), acc[gb][ti], 0, 0, 0);
                    if (kt + 2 < 16) {
#pragma unroll
                        for (int gb = 0; gb < 4; ++gb)
#pragma unroll
                            for (int ti = 0; ti < 2; ++ti)
                                us0[gb * 2 + ti] = sb[(kt + 2) * 4096 + gb * 256 + w32 + ti * 16];
                    }
                }
            }
            __builtin_amdgcn_s_setprio(0);

            float zg[4];
#pragma unroll
            for (int gb = 0; gb < 4; ++gb)
                zg[gb] = (ti_sel ? acc[gb][1][0] : acc[gb][0][0]) + b1c[gb];

            c = sig_(zg[1]) * c + sig_(zg[0]) * tanh_(zg[2]);
            float h = sig_(zg[3]) * tanh_(c);

            if (primary) {
                hbuf[nxt][256 + hcol] = f16b(h);
                out[obase] = h;
            }
            if (t + 1 < T && tid < 128)
                ((uint_t*)&hbuf[nxt][0])[tid] = h1r;
            obase += HID;

            __syncthreads();
        }
    }
}

// ---------------- launch ----------------

extern "C" void kernel_launch(void* const* d_in, const int* in_sizes, int n_in,
                              void* d_out, int out_size, void* d_ws, size_t ws_size,
                              hipStream_t stream) {
    const float* x  = (const float*)d_in[0];
    const float* W0 = (const float*)d_in[1];
    const float* U0 = (const float*)d_in[2];
    const float* b0 = (const float*)d_in[3];
    const float* W1 = (const float*)d_in[4];
    const float* U1 = (const float*)d_in[5];
    const float* b1 = (const float*)d_in[6];
    float* out = (float*)d_out;

    const size_t M = (size_t)BATCH * SEQT;   // 32768

    char* ws = (char*)d_ws;
    ushort_t* xf16  = (ushort_t*)(ws);                         // 16 MB @ 0
    uint_t*   y1pk  = (uint_t*)  (ws + (16u << 20));           // 16 MB @ 16M
    ushort_t* Wt0   = (ushort_t*)(ws + (32u << 20));           // 0.5 MB @ 32M
    u32x4*    Upk0  = (u32x4*)   (ws + (32u << 20) + 524288);  // 0.5 MB @ 32.5M
    u32x4*    Ucmb  = (u32x4*)   (ws + (33u << 20));           // 2 MB @ 33M
    int*      flags = (int*)     (ws + (35u << 20));           // 8 KB @ 35M
    float*    xz    = (float*)   (ws + (36u << 20));           // 128 MB @ 36M

    // reset handoff flags every launch (graph-replay safe)
    hipMemsetAsync(flags, 0, BATCH * 32 * sizeof(int), stream);

    {
        int n4 = (int)(M * DIN / 4);
        cvt_x_kernel<<<dim3((n4 + 255) / 256), dim3(256), 0, stream>>>(x, xf16, n4);
        prep_wt_kernel<<<dim3(1024), dim3(256), 0, stream>>>(W0, Wt0);
        prep_upk_kernel<<<dim3(128), dim3(256), 0, stream>>>(U0, (uint4*)Upk0);
        prep_ucmb_kernel<<<dim3(256), dim3(256), 0, stream>>>(W1, U1, (uint4*)Ucmb);
    }

    // layer-1 input projection (GEMM); layer-2 projection is folded into the
    // consumer recurrence (K=512), so no GEMM2.
    gemm_f16_kernel<<<dim3((int)(M / 128) * 8), dim3(256), 0, stream>>>(xf16, Wt0, b0, xz, (int)M);

    // fused pipelined recurrence: 64 producer WGs + 64 consumer WGs
    lstm_pipe_kernel<<<dim3(128), dim3(512), 0, stream>>>(
        xz, Upk0, Ucmb, b1, y1pk, flags, out, SEQT);
}

// Round 11
// 2186.855 us; speedup vs baseline: 5.3595x; 5.3595x over previous
//
#include <hip/hip_runtime.h>

typedef unsigned short ushort_t;
typedef unsigned int uint_t;

using f16x8 = __attribute__((ext_vector_type(8))) _Float16;
using f32x4 = __attribute__((ext_vector_type(4))) float;
using u32x4 = __attribute__((ext_vector_type(4))) unsigned int;

#define BATCH 64
#define SEQT 512
#define DIN 256
#define HID 256
#define G4 1024   // 4*HID
#define CH 64     // pipeline chunk (timesteps)

static __device__ __forceinline__ ushort_t f16b(float x) {
    return __builtin_bit_cast(ushort_t, (_Float16)x);
}
static __device__ __forceinline__ uint_t pk2(float a, float b) {
    return (uint_t)f16b(a) | ((uint_t)f16b(b) << 16);
}
static __device__ __forceinline__ float sig_(float x) {
    return 1.f / (1.f + __expf(-x));
}
static __device__ __forceinline__ float tanh_(float x) {
    float e = __expf(2.f * x);
    return (e - 1.f) / (e + 1.f);
}

#define PINA(x) asm volatile("" : "+a"(x))
#define PINV(x) asm volatile("" : "+v"(x))

static __device__ __forceinline__ f16x8 asf16(u32x4 v) {
    return __builtin_bit_cast(f16x8, v);
}

// ---------------- prep kernels ----------------

__global__ void cvt_x_kernel(const float* __restrict__ in, ushort_t* __restrict__ out, int n4) {
    int i = blockIdx.x * blockDim.x + threadIdx.x;
    if (i < n4) {
        float4 v = ((const float4*)in)[i];
        ushort4 o;
        o.x = f16b(v.x); o.y = f16b(v.y); o.z = f16b(v.z); o.w = f16b(v.w);
        ((ushort4*)out)[i] = o;
    }
}

// W [256][1024] f32 -> Wt [1024][256] f16 bits (transpose)
__global__ void prep_wt_kernel(const float* __restrict__ W, ushort_t* __restrict__ Wt) {
    int tid = blockIdx.x * blockDim.x + threadIdx.x;
    int k = tid >> 10;
    int n = tid & 1023;
    Wt[n * DIN + k] = f16b(W[tid]);
}

// U [256][1024] f32 -> Upk [32][1024] uint4 (f16 pairs, k=8j..8j+7)
__global__ void prep_upk_kernel(const float* __restrict__ U, uint4* __restrict__ Upk) {
    int tid = blockIdx.x * blockDim.x + threadIdx.x;
    int j = tid >> 10;
    int g = tid & 1023;
    uint4 o;
    uint_t* op = &o.x;
#pragma unroll
    for (int q = 0; q < 4; ++q) {
        float a = U[(8 * j + 2 * q) * G4 + g];
        float b = U[(8 * j + 2 * q + 1) * G4 + g];
        op[q] = pk2(a, b);
    }
    Upk[tid] = o;
}

// ---------------- GEMM (layer-1 input projection; unchanged, passing) ----------------

#define GSTRIDE 40

__global__ __launch_bounds__(256) void gemm_f16_kernel(
    const ushort_t* __restrict__ A,
    const ushort_t* __restrict__ Bt,
    const float* __restrict__ bias,
    float* __restrict__ C,
    int M)
{
    const int K = DIN, N = G4;
    __shared__ ushort_t As[128 * GSTRIDE];
    __shared__ ushort_t Bs[128 * GSTRIDE];
    int tid = threadIdx.x;
    int bx = blockIdx.x & 7;
    int by = blockIdx.x >> 3;
    int m0 = by * 128, n0 = bx * 128;
    int w = tid >> 6, lane = tid & 63;
    int wr = (w >> 1) * 64, wc = (w & 1) * 64;
    int r = lane & 15, kg = lane >> 4;

    f32x4 acc[4][4];
#pragma unroll
    for (int i = 0; i < 4; ++i)
#pragma unroll
        for (int j = 0; j < 4; ++j)
            acc[i][j] = f32x4{0.f, 0.f, 0.f, 0.f};

    for (int kt = 0; kt < K; kt += 32) {
        __syncthreads();
#pragma unroll
        for (int s = 0; s < 2; ++s) {
            int chunk = tid + s * 256;
            int row = chunk >> 2;
            int ko = (chunk & 3) * 8;
            uint4 va = *(const uint4*)(A + (size_t)(m0 + row) * K + kt + ko);
            *(uint4*)(&As[row * GSTRIDE + ko]) = va;
            uint4 vb = *(const uint4*)(Bt + (size_t)(n0 + row) * K + kt + ko);
            *(uint4*)(&Bs[row * GSTRIDE + ko]) = vb;
        }
        __syncthreads();
        f16x8 af[4], bf[4];
#pragma unroll
        for (int i = 0; i < 4; ++i) {
            af[i] = *(const f16x8*)(&As[(wr + i * 16 + r) * GSTRIDE + kg * 8]);
            bf[i] = *(const f16x8*)(&Bs[(wc + i * 16 + r) * GSTRIDE + kg * 8]);
        }
#pragma unroll
        for (int i = 0; i < 4; ++i)
#pragma unroll
            for (int j = 0; j < 4; ++j)
                acc[i][j] = __builtin_amdgcn_mfma_f32_16x16x32_f16(af[i], bf[j], acc[i][j], 0, 0, 0);
    }

#pragma unroll
    for (int i = 0; i < 4; ++i)
#pragma unroll
        for (int j = 0; j < 4; ++j) {
            int col = n0 + wc + j * 16 + r;
            float bv = bias[col];
#pragma unroll
            for (int v = 0; v < 4; ++v) {
                int rowg = m0 + wr + i * 16 + kg * 4 + v;
                C[(size_t)rowg * N + col] = acc[i][j][v] + bv;
            }
        }
}

// ---------------- fused chunk-pipelined 2-layer recurrence ----------------
// 128 WGs x 256 thr (4 waves). Blocks 0-63: layer-1 rec (r7 structure),
// packed-u32 ATOMIC(agent) h1 stores + release flag per 64-step chunk.
// Blocks 64-127: layer-2 rec; per chunk: tid0 acquire-poll + barrier,
// atomic-load y1 chunk into LDS, mini-GEMM xz2 = y1@W1t + b1, 64 steps.
// U frags: kt0-3 pinned AGPR, kt4-5 pinned VGPR, kt6-7 LDS. During steps
// the consumer touches only regs/LDS/own-XCD xz2 (no acquire poison).

__global__ __launch_bounds__(256)
__attribute__((amdgpu_waves_per_eu(1, 1)))
void lstm_fused_kernel(
    const float* __restrict__ xz1,     // [B*T][1024] layer-1 xz (bias incl)
    const u32x4* __restrict__ Upk0,    // [32][1024]
    const u32x4* __restrict__ Upk1,    // [32][1024]
    const ushort_t* __restrict__ Wt1,  // [1024][256] f16
    const float* __restrict__ b1,      // [1024]
    uint_t* y1pk,                      // [B*T][128] packed h1 (u32 = 2 f16)
    int* flags,                        // [B][32] (128-B stride)
    float* xz2ws,                      // [B][CH][1024] f32 scratch
    float* out,                        // [B*T][256]
    int T)
{
    __shared__ __align__(16) u32x4 Uld[4][2][16][64];   // 128 KB
    __shared__ __align__(16) ushort_t ys[32][264];      // 16.5 KB (rec2 A-stage)
    __shared__ __align__(16) ushort_t h16[2][HID];      // 1 KB

    const int tid = threadIdx.x;
    const int w = tid >> 6;          // wave 0..3
    const int l = tid & 63;
    const int lg = l >> 4;           // lane group 0..3
    const int lr = l & 15;
    const int role = (int)(blockIdx.x >> 6);
    const int b = (int)(blockIdx.x & 63);

    const int hcol = w * 64 + lg * 16 + lr;
    const u32x4* Upk = role ? Upk1 : Upk0;
    int* flagp = flags + b * 32;

    // ---- preload U fragments (r7 layout: fi = gb*4+ti, ti=0..3) ----
    u32x4 ua[64];   // kt0-3 -> AGPR
    u32x4 uv[32];   // kt4-5 -> VGPR
#pragma unroll
    for (int gb = 0; gb < 4; ++gb)
#pragma unroll
        for (int ti = 0; ti < 4; ++ti) {
            int col = (gb * 16 + w * 4 + ti) * 16 + lr;
            int fi = gb * 4 + ti;
#pragma unroll
            for (int kt = 0; kt < 4; ++kt)
                ua[fi * 4 + kt] = Upk[(kt * 4 + lg) * 1024 + col];
#pragma unroll
            for (int k2 = 0; k2 < 2; ++k2)
                uv[fi * 2 + k2] = Upk[((4 + k2) * 4 + lg) * 1024 + col];
        }
#pragma unroll
    for (int i = 0; i < 64; ++i) PINA(ua[i]);
#pragma unroll
    for (int i = 0; i < 32; ++i) PINV(uv[i]);

#pragma unroll
    for (int gb = 0; gb < 4; ++gb)
#pragma unroll
        for (int ti = 0; ti < 4; ++ti) {
            int col = (gb * 16 + w * 4 + ti) * 16 + lr;
            int fi = gb * 4 + ti;
#pragma unroll
            for (int k2 = 0; k2 < 2; ++k2)
                Uld[w][k2][fi][l] = Upk[((6 + k2) * 4 + lg) * 1024 + col];
        }

    h16[0][tid] = 0;
    float c = 0.f;

    if (role == 0) {
        // ================= layer-1 producer =================
        const float* xz_b = xz1 + (size_t)b * T * G4;
        float xzc[4];
#pragma unroll
        for (int gb = 0; gb < 4; ++gb) xzc[gb] = xz_b[gb * 256 + hcol];
        __syncthreads();

        for (int t = 0; t < T; ++t) {
            const int cur = t & 1, nxt = cur ^ 1;

            f16x8 af[8];
#pragma unroll
            for (int kt = 0; kt < 8; ++kt)
                af[kt] = *(const f16x8*)((const char*)&h16[cur][0] + kt * 64 + lg * 16);

            float xzn[4];
            {
                const float* xztn = xz_b + (size_t)((t + 1 < T) ? (t + 1) : t) * G4;
#pragma unroll
                for (int gb = 0; gb < 4; ++gb) xzn[gb] = xztn[gb * 256 + hcol];
            }

            float zg[4];
#pragma unroll
            for (int gb = 0; gb < 4; ++gb) {
                f32x4 accA[4], accB[4];
#pragma unroll
                for (int ti = 0; ti < 4; ++ti) {
                    accA[ti] = f32x4{0.f, 0.f, 0.f, 0.f};
                    accB[ti] = f32x4{0.f, 0.f, 0.f, 0.f};
                }
#pragma unroll
                for (int ti = 0; ti < 4; ++ti) {
                    int fi = gb * 4 + ti;
#pragma unroll
                    for (int kt = 0; kt < 4; ++kt)
                        accA[ti] = __builtin_amdgcn_mfma_f32_16x16x32_f16(
                            af[kt], asf16(ua[fi * 4 + kt]), accA[ti], 0, 0, 0);
#pragma unroll
                    for (int k2 = 0; k2 < 2; ++k2)
                        accB[ti] = __builtin_amdgcn_mfma_f32_16x16x32_f16(
                            af[4 + k2], asf16(uv[fi * 2 + k2]), accB[ti], 0, 0, 0);
#pragma unroll
                    for (int k2 = 0; k2 < 2; ++k2) {
                        u32x4 ub = Uld[w][k2][fi][l];
                        accB[ti] = __builtin_amdgcn_mfma_f32_16x16x32_f16(
                            af[6 + k2], asf16(ub), accB[ti], 0, 0, 0);
                    }
                }
                float za = (lg == 0) ? accA[0][0] : (lg == 1) ? accA[1][0]
                         : (lg == 2) ? accA[2][0] : accA[3][0];
                float zb = (lg == 0) ? accB[0][0] : (lg == 1) ? accB[1][0]
                         : (lg == 2) ? accB[2][0] : accB[3][0];
                zg[gb] = za + zb + xzc[gb];
            }

            c = sig_(zg[1]) * c + sig_(zg[0]) * tanh_(zg[2]);
            float h = sig_(zg[3]) * tanh_(c);

            h16[nxt][hcol] = f16b(h);
            // packed atomic handoff (agent scope -> coherence point, r9-proven)
            {
                uint_t hb = (uint_t)f16b(h);
                uint_t pb = (uint_t)(unsigned)__shfl_xor((int)hb, 1);
                if (!(l & 1)) {
                    uint_t pk = hb | (pb << 16);
                    __hip_atomic_store(&y1pk[(size_t)(b * T + t) * 128 + (hcol >> 1)], pk,
                                       __ATOMIC_RELAXED, __HIP_MEMORY_SCOPE_AGENT);
                }
            }
#pragma unroll
            for (int gb = 0; gb < 4; ++gb) xzc[gb] = xzn[gb];

            __syncthreads();   // all lanes' stores drained before flag
            if ((t & (CH - 1)) == (CH - 1) && tid == 0)
                __hip_atomic_store(flagp, (t + 1) / CH, __ATOMIC_RELEASE,
                                   __HIP_MEMORY_SCOPE_AGENT);
        }
    } else {
        // ================= layer-2 consumer =================
        float* xz2row = xz2ws + (size_t)b * (CH * G4);
        float b1w[16];
#pragma unroll
        for (int ct = 0; ct < 16; ++ct) b1w[ct] = b1[(w * 16 + ct) * 16 + lr];
        size_t obase = (size_t)b * T * HID + hcol;
        __syncthreads();

        const int NCH = T / CH;
        for (int ch = 0; ch < NCH; ++ch) {
            // tid0 acquire-poll, then barrier (one L2-inv per chunk)
            if (tid == 0) {
                while (__hip_atomic_load(flagp, __ATOMIC_ACQUIRE, __HIP_MEMORY_SCOPE_AGENT) < ch + 1)
                    __builtin_amdgcn_s_sleep(32);
            }
            __syncthreads();

            // ---- mini-GEMM: xz2[64][1024] = y1_chunk[64][256] @ W1t + b1 ----
#pragma unroll
            for (int half = 0; half < 2; ++half) {
                __syncthreads();
                // stage 32 rows x 128 packed-u32 via agent atomics (always fresh)
#pragma unroll
                for (int it = 0; it < 16; ++it) {
                    int idx = it * 256 + tid;            // 0..4095
                    int row = idx >> 7;                  // 0..31
                    int j = idx & 127;                   // 0..127
                    uint_t v = __hip_atomic_load(
                        &y1pk[(size_t)(b * T + ch * CH + half * 32 + row) * 128 + j],
                        __ATOMIC_RELAXED, __HIP_MEMORY_SCOPE_AGENT);
                    *(uint_t*)&ys[row][2 * j] = v;
                }
                __syncthreads();
#pragma unroll
                for (int ct = 0; ct < 16; ++ct) {
                    int ctI = w * 16 + ct;
                    u32x4 bf[8];
#pragma unroll
                    for (int kt = 0; kt < 8; ++kt)
                        bf[kt] = *(const u32x4*)(Wt1 + (size_t)(ctI * 16 + lr) * DIN + kt * 32 + lg * 8);
                    f32x4 acc[2];
                    acc[0] = f32x4{0.f, 0.f, 0.f, 0.f};
                    acc[1] = f32x4{0.f, 0.f, 0.f, 0.f};
#pragma unroll
                    for (int rt = 0; rt < 2; ++rt)
#pragma unroll
                        for (int kt = 0; kt < 8; ++kt) {
                            f16x8 af = *(const f16x8*)&ys[rt * 16 + lr][kt * 32 + lg * 8];
                            acc[rt] = __builtin_amdgcn_mfma_f32_16x16x32_f16(
                                af, asf16(bf[kt]), acc[rt], 0, 0, 0);
                        }
                    // C: row=(lane>>4)*4+v, col=lane&15 (verified layout)
#pragma unroll
                    for (int rt = 0; rt < 2; ++rt)
#pragma unroll
                        for (int v = 0; v < 4; ++v) {
                            int row = half * 32 + rt * 16 + lg * 4 + v;
                            xz2row[(size_t)row * G4 + ctI * 16 + lr] = acc[rt][v] + b1w[ct];
                        }
                }
            }
            __syncthreads();

            // ---- 64 recurrence steps (regs/LDS/own-XCD xz2 only) ----
            for (int tb = 0; tb < CH; ++tb) {
                const int t = ch * CH + tb;
                const int cur = t & 1, nxt = cur ^ 1;

                float xzc[4];
#pragma unroll
                for (int gb = 0; gb < 4; ++gb)
                    xzc[gb] = xz2row[(size_t)tb * G4 + gb * 256 + hcol];

                f16x8 af[8];
#pragma unroll
                for (int kt = 0; kt < 8; ++kt)
                    af[kt] = *(const f16x8*)((const char*)&h16[cur][0] + kt * 64 + lg * 16);

                float zg[4];
#pragma unroll
                for (int gb = 0; gb < 4; ++gb) {
                    f32x4 accA[4], accB[4];
#pragma unroll
                    for (int ti = 0; ti < 4; ++ti) {
                        accA[ti] = f32x4{0.f, 0.f, 0.f, 0.f};
                        accB[ti] = f32x4{0.f, 0.f, 0.f, 0.f};
                    }
#pragma unroll
                    for (int ti = 0; ti < 4; ++ti) {
                        int fi = gb * 4 + ti;
#pragma unroll
                        for (int kt = 0; kt < 4; ++kt)
                            accA[ti] = __builtin_amdgcn_mfma_f32_16x16x32_f16(
                                af[kt], asf16(ua[fi * 4 + kt]), accA[ti], 0, 0, 0);
#pragma unroll
                        for (int k2 = 0; k2 < 2; ++k2)
                            accB[ti] = __builtin_amdgcn_mfma_f32_16x16x32_f16(
                                af[4 + k2], asf16(uv[fi * 2 + k2]), accB[ti], 0, 0, 0);
#pragma unroll
                        for (int k2 = 0; k2 < 2; ++k2) {
                            u32x4 ub = Uld[w][k2][fi][l];
                            accB[ti] = __builtin_amdgcn_mfma_f32_16x16x32_f16(
                                af[6 + k2], asf16(ub), accB[ti], 0, 0, 0);
                        }
                    }
                    float za = (lg == 0) ? accA[0][0] : (lg == 1) ? accA[1][0]
                             : (lg == 2) ? accA[2][0] : accA[3][0];
                    float zb = (lg == 0) ? accB[0][0] : (lg == 1) ? accB[1][0]
                             : (lg == 2) ? accB[2][0] : accB[3][0];
                    zg[gb] = za + zb + xzc[gb];
                }

                c = sig_(zg[1]) * c + sig_(zg[0]) * tanh_(zg[2]);
                float h = sig_(zg[3]) * tanh_(c);

                h16[nxt][hcol] = f16b(h);
                out[obase] = h;
                obase += HID;

                __syncthreads();
            }
        }
    }
}

// ---------------- launch ----------------

extern "C" void kernel_launch(void* const* d_in, const int* in_sizes, int n_in,
                              void* d_out, int out_size, void* d_ws, size_t ws_size,
                              hipStream_t stream) {
    const float* x  = (const float*)d_in[0];
    const float* W0 = (const float*)d_in[1];
    const float* U0 = (const float*)d_in[2];
    const float* b0 = (const float*)d_in[3];
    const float* W1 = (const float*)d_in[4];
    const float* U1 = (const float*)d_in[5];
    const float* b1 = (const float*)d_in[6];
    float* out = (float*)d_out;

    const size_t M = (size_t)BATCH * SEQT;   // 32768

    char* ws = (char*)d_ws;
    ushort_t* xf16  = (ushort_t*)(ws);                         // 16 MB @ 0 (dead after GEMM1)
    float*    xz2ws = (float*)   (ws);                         // aliases xf16 (16 MB)
    uint_t*   y1pk  = (uint_t*)  (ws + (16u << 20));           // 16 MB @ 16M
    ushort_t* Wt0   = (ushort_t*)(ws + (32u << 20));           // 0.5 MB @ 32M
    ushort_t* Wt1   = (ushort_t*)(ws + (32u << 20) + 524288);  // 0.5 MB @ 32.5M
    u32x4*    Upk0  = (u32x4*)   (ws + (33u << 20));           // 0.5 MB @ 33M
    u32x4*    Upk1  = (u32x4*)   (ws + (33u << 20) + 524288);  // 0.5 MB @ 33.5M
    int*      flags = (int*)     (ws + (34u << 20));           // 8 KB @ 34M
    float*    xz1   = (float*)   (ws + (35u << 20));           // 128 MB @ 35M

    // reset handoff flags every launch (graph-replay safe)
    hipMemsetAsync(flags, 0, BATCH * 32 * sizeof(int), stream);

    {
        int n4 = (int)(M * DIN / 4);
        cvt_x_kernel<<<dim3((n4 + 255) / 256), dim3(256), 0, stream>>>(x, xf16, n4);
        prep_wt_kernel<<<dim3(1024), dim3(256), 0, stream>>>(W0, Wt0);
        prep_wt_kernel<<<dim3(1024), dim3(256), 0, stream>>>(W1, Wt1);
        prep_upk_kernel<<<dim3(128), dim3(256), 0, stream>>>(U0, (uint4*)Upk0);
        prep_upk_kernel<<<dim3(128), dim3(256), 0, stream>>>(U1, (uint4*)Upk1);
    }

    // layer-1 input projection
    gemm_f16_kernel<<<dim3((int)(M / 128) * 8), dim3(256), 0, stream>>>(xf16, Wt0, b0, xz1, (int)M);

    // fused chunk-pipelined 2-layer recurrence (layer-2 projection folded in)
    lstm_fused_kernel<<<dim3(128), dim3(256), 0, stream>>>(
        xz1, Upk0, Upk1, Wt1, b1, y1pk, flags, xz2ws, out, SEQT);
}